// Round 1
// baseline (18.270 us; speedup 1.0000x reference)
//
#include <hip/hip_runtime.h>

#define BLK 256

__global__ __launch_bounds__(BLK) void dlt_solve_kernel(
    const float* __restrict__ corners,  // (8, B) layout: [comp*B + i], comp = k*2 + {0:y,1:x}
    const float* __restrict__ h4pt,     // (B, 8)
    float* __restrict__ out,            // (B, 9) -> (B,3,3)
    int B)
{
    __shared__ __align__(16) float sout[BLK * 9];
    const int tid = threadIdx.x;
    const int i = blockIdx.x * BLK + tid;

    float x[8];
    if (i < B) {
        // ---- load inputs ----
        const float4* h4 = reinterpret_cast<const float4*>(h4pt + (size_t)i * 8);
        float4 d0 = h4[0];
        float4 d1 = h4[1];
        float dy[4] = {d0.x, d0.z, d1.x, d1.z};
        float dx[4] = {d0.y, d0.w, d1.y, d1.w};

        float ya[4], xa[4], yb[4], xb[4];
#pragma unroll
        for (int k = 0; k < 4; ++k) {
            ya[k] = corners[(size_t)(2 * k + 0) * B + i];
            xa[k] = corners[(size_t)(2 * k + 1) * B + i];
            yb[k] = ya[k] + dy[k];
            xb[k] = xa[k] + dx[k];
        }

        // ---- build A (8x8) and rhs b (8) ----
        float A[8][8], bb[8];
#pragma unroll
        for (int k = 0; k < 4; ++k) {
            float* r1 = A[2 * k];
            float* r2 = A[2 * k + 1];
            r1[0] = 0.f;   r1[1] = 0.f;   r1[2] = 0.f;
            r1[3] = -ya[k]; r1[4] = -xa[k]; r1[5] = -1.f;
            r1[6] = xb[k] * ya[k]; r1[7] = xb[k] * xa[k];
            r2[0] = ya[k]; r2[1] = xa[k]; r2[2] = 1.f;
            r2[3] = 0.f;   r2[4] = 0.f;   r2[5] = 0.f;
            r2[6] = -yb[k] * ya[k]; r2[7] = -yb[k] * xa[k];
            bb[2 * k]     = -xb[k];
            bb[2 * k + 1] =  yb[k];
        }

        // ---- Gaussian elimination with partial pivoting (fully unrolled,
        //      all indices compile-time; swaps via per-element cndmask) ----
#pragma unroll
        for (int k = 0; k < 8; ++k) {
            // bubble the max-|pivot| row into position k
#pragma unroll
            for (int j = k + 1; j < 8; ++j) {
                bool sw = fabsf(A[j][k]) > fabsf(A[k][k]);
#pragma unroll
                for (int c = k; c < 8; ++c) {
                    float t0 = A[k][c], t1 = A[j][c];
                    A[k][c] = sw ? t1 : t0;
                    A[j][c] = sw ? t0 : t1;
                }
                float t0 = bb[k], t1 = bb[j];
                bb[k] = sw ? t1 : t0;
                bb[j] = sw ? t0 : t1;
            }
            float inv = 1.0f / A[k][k];
#pragma unroll
            for (int j = k + 1; j < 8; ++j) {
                float f = A[j][k] * inv;
#pragma unroll
                for (int c = k + 1; c < 8; ++c)
                    A[j][c] = fmaf(-f, A[k][c], A[j][c]);
                bb[j] = fmaf(-f, bb[k], bb[j]);
            }
        }

        // ---- back substitution ----
#pragma unroll
        for (int k = 7; k >= 0; --k) {
            float s = bb[k];
#pragma unroll
            for (int c = k + 1; c < 8; ++c)
                s = fmaf(-A[k][c], x[c], s);
            x[k] = s / A[k][k];
        }
    } else {
#pragma unroll
        for (int k = 0; k < 8; ++k) x[k] = 0.f;
    }

    // ---- stage result in LDS, then coalesced float4 block write ----
#pragma unroll
    for (int k = 0; k < 8; ++k) sout[tid * 9 + k] = x[k];
    sout[tid * 9 + 8] = 1.0f;
    __syncthreads();

    const size_t base = (size_t)blockIdx.x * BLK * 9;  // floats
    const size_t total = (size_t)B * 9;
    if (base + (size_t)BLK * 9 <= total) {
        // full block: vectorized coalesced copy (base*4 bytes % 16 == 0)
        float4* out4 = reinterpret_cast<float4*>(out + base);
        const float4* s4 = reinterpret_cast<const float4*>(sout);
        constexpr int NV = BLK * 9 / 4;  // 576
#pragma unroll
        for (int v = tid; v < NV; v += BLK) out4[v] = s4[v];
    } else {
        // tail block: guarded scalar copy
        for (int v = tid; v < BLK * 9; v += BLK) {
            size_t g = base + v;
            if (g < total) out[g] = sout[v];
        }
    }
}

extern "C" void kernel_launch(void* const* d_in, const int* in_sizes, int n_in,
                              void* d_out, int out_size, void* d_ws, size_t ws_size,
                              hipStream_t stream) {
    const float* corners = (const float*)d_in[0];  // (8, B) float32
    const float* h4pt    = (const float*)d_in[1];  // (B, 8) float32
    float* out = (float*)d_out;                    // (B, 3, 3) float32
    const int B = in_sizes[0] / 8;
    const int grid = (B + BLK - 1) / BLK;
    dlt_solve_kernel<<<grid, BLK, 0, stream>>>(corners, h4pt, out, B);
}

// Round 2
// 14.084 us; speedup vs baseline: 1.2972x; 1.2972x over previous
//
#include <hip/hip_runtime.h>

#define BLK 256

__global__ __launch_bounds__(BLK) void dlt_solve_kernel(
    const float* __restrict__ corners,  // (8, B): [comp*B + i], comp = k*2 + {0:y,1:x}
    const float* __restrict__ h4pt,     // (B, 8)
    float* __restrict__ out,            // (B, 9) -> (B,3,3)
    int B)
{
    __shared__ __align__(16) float sout[BLK * 9];
    const int tid = threadIdx.x;
    const int i = blockIdx.x * BLK + tid;

    float h[9];
    if (i < B) {
        // ---- load inputs ----
        const float4* h4 = reinterpret_cast<const float4*>(h4pt + (size_t)i * 8);
        float4 d0 = h4[0];
        float4 d1 = h4[1];
        float dy[4] = {d0.x, d0.z, d1.x, d1.z};
        float dx[4] = {d0.y, d0.w, d1.y, d1.w};

        float ya[4], xa[4], yb[4], xb[4];
#pragma unroll
        for (int k = 0; k < 4; ++k) {
            ya[k] = corners[(size_t)(2 * k + 0) * B + i];
            xa[k] = corners[(size_t)(2 * k + 1) * B + i];
            yb[k] = ya[k] + dy[k];
            xb[k] = xa[k] + dx[k];
        }

        // ---- left null-vector of M = [[ya_k, xa_k, 1]] (4x3):
        //      n_k = (-1)^k * det(M minor deleting row k)  =>  n^T M = 0 ----
        auto D3 = [&](int a, int b, int c) {
            return (ya[b] - ya[a]) * (xa[c] - xa[a]) - (ya[c] - ya[a]) * (xa[b] - xa[a]);
        };
        float D012 = D3(0, 1, 2);
        float n0 =  D3(1, 2, 3);
        float n1 = -D3(0, 2, 3);
        float n2 =  D3(0, 1, 3);
        float n3 = -D012;
        float nn[4] = {n0, n1, n2, n3};

        // ---- 2x2 system for w = (h6, h7):
        //  sum_k n_k * xb_k * (ya_k h6 + xa_k h7 + 1) = 0
        //  sum_k n_k * yb_k * (ya_k h6 + xa_k h7 + 1) = 0 ----
        float a00 = 0.f, a01 = 0.f, r0 = 0.f;
        float a10 = 0.f, a11 = 0.f, r1 = 0.f;
#pragma unroll
        for (int k = 0; k < 4; ++k) {
            float tx = nn[k] * xb[k];
            float ty = nn[k] * yb[k];
            a00 = fmaf(tx, ya[k], a00);
            a01 = fmaf(tx, xa[k], a01);
            r0 -= tx;
            a10 = fmaf(ty, ya[k], a10);
            a11 = fmaf(ty, xa[k], a11);
            r1 -= ty;
        }
        float inv2 = 1.0f / (a00 * a11 - a01 * a10);
        float h6 = (r0 * a11 - a01 * r1) * inv2;
        float h7 = (a00 * r1 - r0 * a10) * inv2;

        // ---- back-solve u = (h0,h1,h2), v = (h3,h4,h5) from rows {0,1,2}:
        //  m_k . u = yb_k * s_k ,  m_k . v = xb_k * s_k ,
        //  s_k = ya_k h6 + xa_k h7 + 1.  Cramer, shared det = D012. ----
        float s0 = fmaf(ya[0], h6, fmaf(xa[0], h7, 1.0f));
        float s1 = fmaf(ya[1], h6, fmaf(xa[1], h7, 1.0f));
        float s2 = fmaf(ya[2], h6, fmaf(xa[2], h7, 1.0f));
        float ru0 = yb[0] * s0, ru1 = yb[1] * s1, ru2 = yb[2] * s2;
        float rv0 = xb[0] * s0, rv1 = xb[1] * s1, rv2 = xb[2] * s2;

        float dy1 = ya[1] - ya[0], dy2 = ya[2] - ya[0];
        float dx1 = xa[1] - xa[0], dx2 = xa[2] - xa[0];
        float g0 = ya[1] * xa[2] - ya[2] * xa[1];
        float g1 = ya[0] * xa[2] - ya[2] * xa[0];
        float g2 = ya[0] * xa[1] - ya[1] * xa[0];
        float inv3 = 1.0f / D012;

        float du1 = ru1 - ru0, du2 = ru2 - ru0;
        float dv1 = rv1 - rv0, dv2 = rv2 - rv0;
        h[0] = (du1 * dx2 - du2 * dx1) * inv3;
        h[1] = (dy1 * du2 - dy2 * du1) * inv3;
        h[2] = (ru0 * g0 - ru1 * g1 + ru2 * g2) * inv3;
        h[3] = (dv1 * dx2 - dv2 * dx1) * inv3;
        h[4] = (dy1 * dv2 - dy2 * dv1) * inv3;
        h[5] = (rv0 * g0 - rv1 * g1 + rv2 * g2) * inv3;
        h[6] = h6;
        h[7] = h7;
        h[8] = 1.0f;
    } else {
#pragma unroll
        for (int k = 0; k < 9; ++k) h[k] = 0.f;
    }

    // ---- stage result in LDS, then coalesced float4 block write ----
#pragma unroll
    for (int k = 0; k < 9; ++k) sout[tid * 9 + k] = h[k];
    __syncthreads();

    const size_t base = (size_t)blockIdx.x * BLK * 9;  // floats
    const size_t total = (size_t)B * 9;
    if (base + (size_t)BLK * 9 <= total) {
        float4* out4 = reinterpret_cast<float4*>(out + base);
        const float4* s4 = reinterpret_cast<const float4*>(sout);
        constexpr int NV = BLK * 9 / 4;  // 576
#pragma unroll
        for (int v = tid; v < NV; v += BLK) out4[v] = s4[v];
    } else {
        for (int v = tid; v < BLK * 9; v += BLK) {
            size_t g = base + v;
            if (g < total) out[g] = sout[v];
        }
    }
}

extern "C" void kernel_launch(void* const* d_in, const int* in_sizes, int n_in,
                              void* d_out, int out_size, void* d_ws, size_t ws_size,
                              hipStream_t stream) {
    const float* corners = (const float*)d_in[0];  // (8, B) float32
    const float* h4pt    = (const float*)d_in[1];  // (B, 8) float32
    float* out = (float*)d_out;                    // (B, 3, 3) float32
    const int B = in_sizes[0] / 8;
    const int grid = (B + BLK - 1) / BLK;
    dlt_solve_kernel<<<grid, BLK, 0, stream>>>(corners, h4pt, out, B);
}